// Round 18
// baseline (158.711 us; speedup 1.0000x reference)
//
#include <hip/hip_runtime.h>

// IPA forward, MI355X. B=2,N=512,C_S=384,C_Z=128,H=12,D=16,PQ=4,PV=8,OUT_IN=2112.
// R17: k_attn z staging via __builtin_amdgcn_global_load_lds (width 16, fire-and-forget:
//      64KB in flight/block vs ~8KB with reg-dest loads). z held f32 in LDS (64KB, linear dest,
//      source pre-swizzle L^((L>>9&7)<<4)); bias MFMA + PC read f32+cvtpk. zbfc deleted;
//      attnbF 12 rows. Tail identical to R16 (MFMA proj pipeline).

typedef __attribute__((ext_vector_type(8))) short bf16x8;
typedef __attribute__((ext_vector_type(4))) float f32x4;
typedef __attribute__((ext_vector_type(4))) unsigned int u32x4;
typedef __attribute__((ext_vector_type(2))) unsigned int u32x2;

__device__ __forceinline__ unsigned short f2b(float f) {
  union { float f; unsigned int u; } x; x.f = f;
  unsigned int r = (x.u + 0x7FFFu + ((x.u >> 16) & 1u)) >> 16;
  return (unsigned short)r;
}
__device__ __forceinline__ float b2f(unsigned short u) {
  return __builtin_bit_cast(float, (unsigned int)u << 16);
}
__device__ __forceinline__ unsigned int cvtpk(float lo, float hi) {
  unsigned int r;
  asm("v_cvt_pk_bf16_f32 %0, %1, %2" : "=v"(r) : "v"(lo), "v"(hi));
  return r;
}
__device__ __forceinline__ void gload_lds16(const void* g, void* l) {
  __builtin_amdgcn_global_load_lds(
      (const __attribute__((address_space(1))) void*)g,
      (__attribute__((address_space(3))) void*)l, 16, 0, 0);
}
// concatenated projection weight element W[k][o]
__device__ __forceinline__ float wsrc(const float* wq, const float* wkv,
                                      const float* wqp, const float* wkvp, int k, int o) {
  if (o < 192)  return wq[k * 192 + o];
  if (o < 576)  return wkv[k * 384 + (o - 192)];
  if (o < 720)  return wqp[k * 144 + (o - 576)];
  return wkvp[k * 432 + (o - 720)];
}
__device__ __forceinline__ float bsrc(const float* bq, const float* bkv,
                                      const float* bqp, const float* bkvp, int o) {
  if (o < 192)  return bq[o];
  if (o < 576)  return bkv[o - 192];
  if (o < 720)  return bqp[o - 576];
  return bkvp[o - 720];
}

// ---------------- K0: k_prep — wout transpose (blocks 0..791) + W transpose (792..1223) ----------------
__global__ __launch_bounds__(256) void k_prep(
    const float* __restrict__ wout, unsigned short* __restrict__ woutT,
    const float* __restrict__ wq, const float* __restrict__ wkv,
    const float* __restrict__ wqp, const float* __restrict__ wkvp,
    unsigned short* __restrict__ WT) {
  __shared__ float tile[32][33];
  int tid = threadIdx.x;
  int tx = tid & 31, ty = tid >> 5;
  if (blockIdx.x < 792) {
    int bx = blockIdx.x;
    int kb = (bx % 66) * 32, cb = (bx / 66) * 32;
    #pragma unroll
    for (int r = ty; r < 32; r += 8) tile[r][tx] = wout[(size_t)(kb + r) * 384 + cb + tx];
    __syncthreads();
    #pragma unroll
    for (int r = ty; r < 32; r += 8) woutT[(size_t)(cb + r) * 2112 + kb + tx] = f2b(tile[tx][r]);
  } else {
    int bx = blockIdx.x - 792;
    int kb = (bx % 12) * 32, ob = (bx / 12) * 32;
    #pragma unroll
    for (int r = ty; r < 32; r += 8) tile[r][tx] = wsrc(wq, wkv, wqp, wkvp, kb + r, ob + tx);
    __syncthreads();
    #pragma unroll
    for (int r = ty; r < 32; r += 8) WT[(size_t)(ob + r) * 384 + kb + tx] = f2b(tile[tx][r]);
  }
}

// ---------------- K1: k_projG — C[1024 i][1152 o] = s @ W + b via MFMA, 64x64 tiles ----------------
__global__ __launch_bounds__(256) void k_projG(
    const float* __restrict__ s, const unsigned short* __restrict__ WT,
    const float* __restrict__ bq, const float* __restrict__ bkv,
    const float* __restrict__ bqp, const float* __restrict__ bkvp,
    float* __restrict__ qws,
    unsigned short* __restrict__ kb2, unsigned short* __restrict__ vT,
    float* __restrict__ rawp) {
  int tid = threadIdx.x;
  int wv = tid >> 6, l = tid & 63, lr = l & 15, lk = l >> 4;
  int wm = wv >> 1, wn = wv & 1;
  int i0 = blockIdx.x * 64, o0 = blockIdx.y * 64;
  f32x4 acc[2][2] = {};

  #pragma unroll 3
  for (int ks = 0; ks < 12; ks++) {
    int k0 = ks * 32;
    bf16x8 af[2], bf[2];
    #pragma unroll
    for (int mf = 0; mf < 2; mf++) {
      int i = i0 + wm * 32 + mf * 16 + lr;
      const float4* sp = (const float4*)(s + (size_t)i * 384 + k0);
      float4 a0 = sp[lk * 2], a1 = sp[lk * 2 + 1];
      u32x4 afp;
      afp[0] = cvtpk(a0.x, a0.y); afp[1] = cvtpk(a0.z, a0.w);
      afp[2] = cvtpk(a1.x, a1.y); afp[3] = cvtpk(a1.z, a1.w);
      af[mf] = __builtin_bit_cast(bf16x8, afp);
    }
    #pragma unroll
    for (int nf = 0; nf < 2; nf++) {
      int o = o0 + wn * 32 + nf * 16 + lr;
      bf[nf] = *(const bf16x8*)(WT + (size_t)o * 384 + k0 + lk * 8);
    }
    #pragma unroll
    for (int mf = 0; mf < 2; mf++)
      #pragma unroll
      for (int nf = 0; nf < 2; nf++)
        acc[mf][nf] = __builtin_amdgcn_mfma_f32_16x16x32_bf16(af[mf], bf[nf], acc[mf][nf], 0, 0, 0);
  }

  #pragma unroll
  for (int mf = 0; mf < 2; mf++) {
    #pragma unroll
    for (int nf = 0; nf < 2; nf++) {
      int o = o0 + wn * 32 + nf * 16 + lr;
      float bias = bsrc(bq, bkv, bqp, bkvp, o);
      #pragma unroll
      for (int reg = 0; reg < 4; reg++) {
        int i = i0 + wm * 32 + mf * 16 + lk * 4 + reg;
        float v = acc[mf][nf][reg] + bias;
        int b2 = i >> 9, jj = i & 511;
        if (o < 192) {
          qws[(size_t)i * 192 + o] = v;
        } else if (o < 576) {
          int c = o - 192, h = c >> 5, e = c & 31;
          if (e < 16)
            kb2[(((size_t)b2 * 12 + h) * 512 + jj) * 40 + e] = f2b(v);
          else
            vT[((size_t)b2 * 480 + h * 16 + (e - 16)) * 512 + jj] = f2b(v);
        } else {
          rawp[(size_t)i * 576 + (o - 576)] = v;
        }
      }
    }
  }
}

// ---------------- K2: k_points — rotation/norm epilogue from rawp ----------------
__global__ __launch_bounds__(512) void k_points(
    const float* __restrict__ rawp,
    const float* __restrict__ rot, const float* __restrict__ trn,
    const float* __restrict__ hwt,
    float* __restrict__ qgws, float* __restrict__ qnws,
    unsigned short* __restrict__ kb2, unsigned short* __restrict__ vT) {
  __shared__ float praw[4][576];
  int tid = threadIdx.x;
  int row0 = blockIdx.x * 4;

  for (int idx = tid; idx < 2304; idx += 512)
    praw[idx / 576][idx % 576] = rawp[(size_t)row0 * 576 + idx];
  __syncthreads();

  for (int idx = tid; idx < 768; idx += 512) {
    int r = idx / 192, p = idx % 192;
    int bi = row0 + r;
    int bb2 = bi >> 9, jj = bi & 511;
    const float* Rm = rot + (size_t)bi * 9;
    const float* tv = trn + (size_t)bi * 3;
    float x, y, z;
    if (p < 48) { x = praw[r][p]; y = praw[r][48 + p]; z = praw[r][96 + p]; }
    else { int q = p - 48; x = praw[r][144 + q]; y = praw[r][288 + q]; z = praw[r][432 + q]; }
    float gx = Rm[0] * x + Rm[1] * y + Rm[2] * z + tv[0];
    float gy = Rm[3] * x + Rm[4] * y + Rm[5] * z + tv[1];
    float gz = Rm[6] * x + Rm[7] * y + Rm[8] * z + tv[2];
    if (p < 48) {
      float* dst = qgws + (size_t)bi * 144 + p * 3;
      dst[0] = gx; dst[1] = gy; dst[2] = gz;
    } else {
      int q12 = p - 48; int h = q12 / 12, qq = q12 % 12;
      if (qq < 4) {
        size_t base = (((size_t)bb2 * 12 + h) * 512 + jj) * 40 + 16 + qq * 3;
        kb2[base + 0] = f2b(gx); kb2[base + 1] = f2b(gy); kb2[base + 2] = f2b(gz);
      } else {
        size_t base = ((size_t)bb2 * 480 + 192 + h * 24 + (qq - 4) * 3) * 512 + jj;
        vT[base] = f2b(gx); vT[base + 512] = f2b(gy); vT[base + 1024] = f2b(gz);
      }
    }
  }

  if (tid < 48) {
    int r = tid / 12, h = tid % 12;
    int bi = row0 + r;
    int bb2 = bi >> 9, jj = bi & 511;
    const float* Rm = rot + (size_t)bi * 9;
    const float* tv = trn + (size_t)bi * 3;
    float hw = 0.5f * logf(1.0f + __expf(hwt[h])) * 0.13608276348795434f;
    float qn = 0.f, kn = 0.f;
    #pragma unroll
    for (int qq = 0; qq < 4; qq++) {
      {
        int p = h * 4 + qq;
        float x = praw[r][p], y = praw[r][48 + p], z = praw[r][96 + p];
        float gx = Rm[0]*x + Rm[1]*y + Rm[2]*z + tv[0];
        float gy = Rm[3]*x + Rm[4]*y + Rm[5]*z + tv[1];
        float gz = Rm[6]*x + Rm[7]*y + Rm[8]*z + tv[2];
        qn += gx*gx + gy*gy + gz*gz;
      }
      {
        int q = h * 12 + qq;
        float x = praw[r][144 + q], y = praw[r][288 + q], z = praw[r][432 + q];
        float gx = Rm[0]*x + Rm[1]*y + Rm[2]*z + tv[0];
        float gy = Rm[3]*x + Rm[4]*y + Rm[5]*z + tv[1];
        float gz = Rm[6]*x + Rm[7]*y + Rm[8]*z + tv[2];
        kn += gx*gx + gy*gy + gz*gz;
      }
    }
    qnws[(size_t)bi * 12 + h] = qn;
    float pr = -hw * kn;
    unsigned short hi = f2b(pr);
    unsigned short lo = f2b(pr - b2f(hi));
    size_t base = (((size_t)bb2 * 12 + h) * 512 + jj) * 40;
    kb2[base + 28] = hi; kb2[base + 29] = lo;
    kb2[base + 30] = 0x3F80; kb2[base + 31] = 0x3F80;
  }
}

// ---------------- K3: qkpa per-(b,h) GEMM, 64-i chunks (192 blocks) ----------------
__global__ __launch_bounds__(256) void k_qkpa(
    const float* __restrict__ qws, const float* __restrict__ qgws,
    const float* __restrict__ qnws, const float* __restrict__ hwt,
    const float* __restrict__ mrow,
    const unsigned short* __restrict__ kb2,
    float* __restrict__ qkpa) {
  __shared__ unsigned short aq[64 * 40];
  __shared__ float mI[64];
  __shared__ float mJ[512];
  int bh = blockIdx.x;
  int b = bh / 12, h = bh - b * 12;
  int i0 = blockIdx.y * 64;
  int tid = threadIdx.x;
  float hw = 0.5f * logf(1.0f + __expf(hwt[h])) * 0.13608276348795434f;

  for (int idx = tid; idx < 512; idx += 256) mJ[idx] = mrow[b * 512 + idx];
  if (tid < 64) mI[tid] = mrow[b * 512 + i0 + tid];
  {
    int r = tid >> 2, c0 = (tid & 3) * 10;
    size_t gi = (size_t)b * 512 + i0 + r;
    const float* qr = qws + gi * 192 + h * 16;
    const float* gr = qgws + gi * 144 + h * 12;
    float pr = -hw * qnws[gi * 12 + h];
    unsigned short hi = f2b(pr);
    unsigned short lo = f2b(pr - b2f(hi));
    for (int c = c0; c < c0 + 10; c++) {
      unsigned short v;
      if (c < 16)      v = f2b(0.14433756729740643f * qr[c]);
      else if (c < 28) v = f2b(2.0f * hw * gr[c - 16]);
      else if (c < 30) v = 0x3F80;
      else if (c == 30) v = hi;
      else              v = lo;
      aq[r * 40 + c] = v;
    }
  }
  __syncthreads();

  int w = tid >> 6, l = tid & 63, lr = l & 15, lk = l >> 4;
  int n0 = w * 128;
  bf16x8 afr[4];
  #pragma unroll
  for (int mf = 0; mf < 4; mf++)
    afr[mf] = *(const bf16x8*)&aq[(mf * 16 + lr) * 40 + lk * 8];
  const unsigned short* kbb = kb2 + (size_t)bh * 512 * 40;
  #pragma unroll 2
  for (int nf = 0; nf < 8; nf++) {
    int j = n0 + nf * 16 + lr;
    float mjv = mJ[j];
    bf16x8 bfr = *(const bf16x8*)(kbb + (size_t)j * 40 + lk * 8);
    #pragma unroll
    for (int mf = 0; mf < 4; mf++) {
      f32x4 acc = {0.f, 0.f, 0.f, 0.f};
      acc = __builtin_amdgcn_mfma_f32_16x16x32_bf16(afr[mf], bfr, acc, 0, 0, 0);
      #pragma unroll
      for (int r = 0; r < 4; r++) {
        int il = mf * 16 + lk * 4 + r;
        int i = i0 + il;
        float val = acc[r] + 100000.0f * (mI[il] * mjv - 1.0f);
        qkpa[((size_t)(b * 512 + i) * 12 + h) * 512 + j] = val;
      }
    }
  }
}

// ---------------- K4: fused per (b,i), chunked flash-style + global_load_lds z staging ----------------
__global__ __launch_bounds__(512, 1) void k_attn(
    const float* __restrict__ z,
    const float* __restrict__ wb, const float* __restrict__ bb,
    const float* __restrict__ qkpa,
    unsigned short* __restrict__ attnG,
    unsigned short* __restrict__ feats) {
  __shared__ __align__(16) char zf32c[65536];            // [128 j][128 c] f32, src-preswizzled
  __shared__ __align__(16) unsigned short attnbF[6144];  // [12 h][512 j] bf16 swizzled
  __shared__ __align__(16) float logitsC[12][132];
  __shared__ unsigned short wbT[1536];                   // [12 h][128 c] bf16
  __shared__ float bbl[16];
  __shared__ float mrun[12], lrun[12], frh[16], m_used[12][4], rinv[16];

  int tid = threadIdx.x;
  int bi = blockIdx.x;
  int b = bi >> 9;
  const char* zbaseB = (const char*)(z + (size_t)bi * 65536);
  int wv = tid >> 6, l = tid & 63, lr = l & 15, lk = l >> 4;

  if (tid < 16) bbl[tid] = (tid < 12) ? bb[tid] : 0.0f;
  else if (tid >= 16 && tid < 28) { mrun[tid - 16] = -1e30f; lrun[tid - 16] = 0.f; }
  else if (tid >= 28 && tid < 44) frh[tid - 28] = 1.0f;
  for (int idx = tid; idx < 1536; idx += 512) {
    int h = idx >> 7, c = idx & 127;
    wbT[h * 128 + c] = f2b(wb[c * 12 + h]);
  }
  __syncthreads();

  int hcl = (lr < 12) ? lr : 0;   // clamp for B-frag reads (cols >=12 discarded)
  bf16x8 bfrag[4];
  #pragma unroll
  for (int kc = 0; kc < 4; kc++)
    bfrag[kc] = *(const bf16x8*)(wbT + hcl * 128 + kc * 32 + lk * 8);

  f32x4 accPC = {0.f, 0.f, 0.f, 0.f};
  int c0 = wv * 16;
  int ldsbase = wv * 1024 + l * 16;   // per-thread linear slot within 8KB stripe

  #pragma unroll 1
  for (int ch = 0; ch < 4; ch++) {
    int j0 = ch * 128;
    // stage: 8 x global_load_lds (16B), linear LDS dest, pre-swizzled global src
    {
      const char* gchunk = zbaseB + (size_t)j0 * 512;
      #pragma unroll
      for (int q = 0; q < 8; q++) {
        int L = q * 8192 + ldsbase;
        int src = L ^ (((L >> 9) & 7) << 4);
        gload_lds16(gchunk + src, zf32c + (q * 8192 + wv * 1024));
      }
    }
    __syncthreads();   // drains vmcnt -> chunk resident

    // bias MFMA: per wave one 16-j tile; A = z rows (f32 from LDS, cvtpk), B = wbT
    {
      int jb = wv * 16 + lr;
      int sw = (jb & 7) << 4;
      f32x4 acc = {0.f, 0.f, 0.f, 0.f};
      #pragma unroll
      for (int kc = 0; kc < 4; kc++) {
        int bbyte = jb * 512 + (kc * 32 + lk * 8) * 4;
        float4 a0 = *(const float4*)(zf32c + (bbyte ^ sw));
        float4 a1 = *(const float4*)(zf32c + ((bbyte + 16) ^ sw));
        u32x4 af;
        af[0] = cvtpk(a0.x, a0.y); af[1] = cvtpk(a0.z, a0.w);
        af[2] = cvtpk(a1.x, a1.y); af[3] = cvtpk(a1.z, a1.w);
        acc = __builtin_amdgcn_mfma_f32_16x16x32_bf16(__builtin_bit_cast(bf16x8, af), bfrag[kc], acc, 0, 0, 0);
      }
      if (lr < 12) {
        #pragma unroll
        for (int reg = 0; reg < 4; reg++)
          logitsC[lr][wv * 16 + lk * 4 + reg] = 0.5773502691896258f * (acc[reg] + bbl[lr]);
      }
    }
    __syncthreads();

    // PBc: qkpa add + online softmax -> attnbF (chunk-scaled exp, bf16)
    if (tid < 384) {
      int h = tid >> 5, g = tid & 31;
      float4 v = *(const float4*)&logitsC[h][g * 4];
      float4 q4 = *(const float4*)(qkpa + (size_t)bi * 6144 + h * 512 + j0 + g * 4);
      v.x += q4.x; v.y += q4.y; v.z += q4.z; v.w += q4.w;
      float pmx = fmaxf(fmaxf(v.x, v.y), fmaxf(v.z, v.w));
      #pragma unroll
      for (int off = 16; off > 0; off >>= 1) pmx = fmaxf(pmx, __shfl_xor(pmx, off, 32));
      float m_old = mrun[h];
      float m_new = fmaxf(m_old, pmx);
      float fr = __expf(m_old - m_new);
      float4 e;
      e.x = __expf(v.x - m_new); e.y = __expf(v.y - m_new);
      e.z = __expf(v.z - m_new); e.w = __expf(v.w - m_new);
      float sm = e.x + e.y + e.z + e.w;
      #pragma unroll
      for (int off = 16; off > 0; off >>= 1) sm += __shfl_xor(sm, off, 32);
      if (g == 0) {
        lrun[h] = lrun[h] * fr + sm;
        mrun[h] = m_new;
        m_used[h][ch] = m_new;
        frh[h] = fr;
      }
      u32x2 ob;
      ob[0] = cvtpk(e.x, e.y); ob[1] = cvtpk(e.z, e.w);
      int j4 = j0 + g * 4;
      int byte = (h * 1024 + j4 * 2) ^ ((h & 7) << 4);
      *(u32x2*)((char*)attnbF + byte) = ob;
    }
    __syncthreads();

    // PCc: out_pair accumulate. A = z c-rows (scalar f32 from LDS, cvtpk), B = attn rows.
    {
      float fr = frh[hcl];
      accPC[0] *= fr; accPC[1] *= fr; accPC[2] *= fr; accPC[3] *= fr;
      #pragma unroll
      for (int jt = 0; jt < 4; jt++) {
        u32x4 afp;
        #pragma unroll
        for (int e2 = 0; e2 < 4; e2++) {
          int ja = jt * 32 + lk * 8 + e2 * 2;
          int jb2 = ja + 1;
          float f1 = *(const float*)(zf32c + ((ja * 512 + (c0 + lr) * 4) ^ ((ja & 7) << 4)));
          float f2 = *(const float*)(zf32c + ((jb2 * 512 + (c0 + lr) * 4) ^ ((jb2 & 7) << 4)));
          afp[e2] = cvtpk(f1, f2);
        }
        int pb = (hcl * 1024 + (j0 + jt * 32 + lk * 8) * 2) ^ ((hcl & 7) << 4);
        bf16x8 pfrag = *(const bf16x8*)((const char*)attnbF + pb);
        accPC = __builtin_amdgcn_mfma_f32_16x16x32_bf16(__builtin_bit_cast(bf16x8, afp), pfrag, accPC, 0, 0, 0);
      }
    }
    __syncthreads();
  }

  if (tid < 16) rinv[tid] = (tid < 12) ? (1.0f / lrun[tid]) : 0.0f;
  __syncthreads();

  size_t fb = (size_t)bi * 2112;

  // attnG write with global fixup exp(m_used - m_final) * rinv
  if (tid < 384) {
    int h = tid >> 5, g = tid & 31;
    float rn = rinv[h];
    float mf = mrun[h];
    unsigned short* gout = attnG + (((size_t)(b * 12 + h) * 512) + (bi & 511)) * 512;
    #pragma unroll
    for (int ch = 0; ch < 4; ch++) {
      float sc = __expf(m_used[h][ch] - mf) * rn;
      int j4 = ch * 128 + g * 4;
      int byte = (h * 1024 + j4 * 2) ^ ((h & 7) << 4);
      u32x2 ob = *(const u32x2*)((const char*)attnbF + byte);
      float f0 = b2f((unsigned short)(ob[0] & 0xffffu)) * sc;
      float f1 = b2f((unsigned short)(ob[0] >> 16)) * sc;
      float f2 = b2f((unsigned short)(ob[1] & 0xffffu)) * sc;
      float f3 = b2f((unsigned short)(ob[1] >> 16)) * sc;
      u32x2 ow;
      ow[0] = cvtpk(f0, f1); ow[1] = cvtpk(f2, f3);
      *(u32x2*)(gout + j4) = ow;
    }
  }

  // out_pair write: h = lr, c = c0 + lk*4 + reg
  if (lr < 12) {
    float rn = rinv[lr];
    u32x2 ow;
    ow[0] = cvtpk(accPC[0] * rn, accPC[1] * rn);
    ow[1] = cvtpk(accPC[2] * rn, accPC[3] * rn);
    *(u32x2*)&feats[fb + 576 + lr * 128 + c0 + lk * 4] = ow;
  }
}

// ---------------- K5: [out_scalar | rpg] per-(b,h) GEMM, 64-i chunks (192 blocks) ----------------
__global__ __launch_bounds__(256) void k_av(
    const unsigned short* __restrict__ attnG, const unsigned short* __restrict__ vT,
    const float* __restrict__ rot, const float* __restrict__ trn,
    unsigned short* __restrict__ feats) {
  __shared__ float sc[64 * 24];
  __shared__ float rotL[64 * 9];
  __shared__ float trnL[64 * 3];
  int bh = blockIdx.x;
  int b = bh / 12, h = bh - b * 12;
  int i0 = blockIdx.y * 64;
  int tid = threadIdx.x;

  for (int idx = tid; idx < 576; idx += 256) rotL[idx] = rot[((size_t)b * 512 + i0) * 9 + idx];
  for (int idx = tid; idx < 192; idx += 256) trnL[idx] = trn[((size_t)b * 512 + i0) * 3 + idx];

  int w = tid >> 6, l = tid & 63, lr = l & 15, lk = l >> 4;
  int iw = w * 16;
  const unsigned short* Abase = attnG + ((size_t)bh * 512 + i0 + iw) * 512;
  const unsigned short* vTb = vT + (size_t)b * 480 * 512;
  int cm[3];
  #pragma unroll
  for (int nf = 0; nf < 3; nf++) {
    int c = nf * 16 + lr;
    cm[nf] = (c < 16) ? (h * 16 + c) : (c < 40 ? 192 + h * 24 + (c - 16) : 0);
  }
  f32x4 acc[3] = {};
  #pragma unroll 2
  for (int jb = 0; jb < 512; jb += 32) {
    bf16x8 a0 = *(const bf16x8*)(Abase + (size_t)lr * 512 + jb + lk * 8);
    #pragma unroll
    for (int nf = 0; nf < 3; nf++) {
      bf16x8 bfr = *(const bf16x8*)(vTb + (size_t)cm[nf] * 512 + jb + lk * 8);
      acc[nf] = __builtin_amdgcn_mfma_f32_16x16x32_bf16(a0, bfr, acc[nf], 0, 0, 0);
    }
  }
  #pragma unroll
  for (int nf = 0; nf < 3; nf++) {
    int c = nf * 16 + lr;
    #pragma unroll
    for (int r = 0; r < 4; r++) {
      int il = iw + lk * 4 + r;
      float v = acc[nf][r];
      if (c < 16) feats[(size_t)(b * 512 + i0 + il) * 2112 + h * 16 + c] = f2b(v);
      else if (c < 40) sc[il * 24 + (c - 16)] = v;
    }
  }
  __syncthreads();
  #pragma unroll
  for (int k2 = 0; k2 < 2; k2++) {
    int itm = tid + k2 * 256;
    int il = itm >> 3, pv = itm & 7;
    float gx = sc[il * 24 + pv * 3 + 0] - trnL[il * 3 + 0];
    float gy = sc[il * 24 + pv * 3 + 1] - trnL[il * 3 + 1];
    float gz = sc[il * 24 + pv * 3 + 2] - trnL[il * 3 + 2];
    const float* R = &rotL[il * 9];
    float lx = R[0] * gx + R[3] * gy + R[6] * gz;
    float ly = R[1] * gx + R[4] * gy + R[7] * gz;
    float lz = R[2] * gx + R[5] * gy + R[8] * gz;
    size_t fb = (size_t)(b * 512 + i0 + il) * 2112;
    feats[fb + 192 + h * 8 + pv] = f2b(lx);
    feats[fb + 288 + h * 8 + pv] = f2b(ly);
    feats[fb + 384 + h * 8 + pv] = f2b(lz);
    feats[fb + 480 + h * 8 + pv] = f2b(sqrtf(lx * lx + ly * ly + lz * lz + 1e-8f));
  }
}

// ---------------- K6: out = (feats @ wout + bout) * mask, 64x32 tiles ----------------
__global__ __launch_bounds__(256) void k_out(const unsigned short* __restrict__ feats,
                                             const unsigned short* __restrict__ woutT,
                                             const float* __restrict__ bout,
                                             const float* __restrict__ mrow,
                                             float* __restrict__ out) {
  __shared__ unsigned short At[2048];
  __shared__ unsigned short Bt[1024];
  int m0 = blockIdx.x * 64, n0 = blockIdx.y * 32;
  int tid = threadIdx.x;
  int wv = tid >> 6, l = tid & 63, lr = l & 15, lk = l >> 4;
  int wm = wv >> 1, wn = wv & 1;
  f32x4 acc[2] = {};
  int sr = tid >> 2, sq = tid & 3;
  const char* fbase = (const char*)feats + (size_t)(m0 + sr) * 4224 + sq * 16;
  int swA = (sr * 64 + sq * 16) ^ ((sr & 7) << 4);
  int rb = tid >> 2, qb = tid & 3;
  const char* bbase = (const char*)woutT + (size_t)(n0 + rb) * 4224 + qb * 16;
  int swB = (rb * 64 + qb * 16) ^ ((rb & 7) << 4);

  uint4 av = *(const uint4*)(fbase);
  uint4 bv = {0, 0, 0, 0};
  if (tid < 128) bv = *(const uint4*)(bbase);
  for (int k0 = 0; k0 < 2112; k0 += 32) {
    __syncthreads();
    *(uint4*)((char*)At + swA) = av;
    if (tid < 128) *(uint4*)((char*)Bt + swB) = bv;
    __syncthreads();
    if (k0 + 32 < 2112) {
      av = *(const uint4*)(fbase + (size_t)(k0 + 32) * 2);
      if (tid < 128) bv = *(const uint4*)(bbase + (size_t)(k0 + 32) * 2);
    }
    bf16x8 af[2], bfv;
    #pragma unroll
    for (int mt = 0; mt < 2; mt++) {
      int row = wm * 32 + mt * 16 + lr;
      af[mt] = *(const bf16x8*)((const char*)At + ((row * 64 + lk * 16) ^ ((row & 7) << 4)));
    }
    {
      int row = wn * 16 + lr;
      bfv = *(const bf16x8*)((const char*)Bt + ((row * 64 + lk * 16) ^ ((row & 7) << 4)));
    }
    #pragma unroll
    for (int mt = 0; mt < 2; mt++)
      acc[mt] = __builtin_amdgcn_mfma_f32_16x16x32_bf16(af[mt], bfv, acc[mt], 0, 0, 0);
  }

  #pragma unroll
  for (int mt = 0; mt < 2; mt++) {
    int nc = n0 + wn * 16 + lr;
    float bo = bout[nc];
    #pragma unroll
    for (int reg = 0; reg < 4; reg++) {
      int rowg = m0 + wm * 32 + mt * 16 + lk * 4 + reg;
      out[(size_t)rowg * 384 + nc] = (acc[mt][reg] + bo) * mrow[rowg];
    }
  }
}

extern "C" void kernel_launch(void* const* d_in, const int* in_sizes, int n_in,
                              void* d_out, int out_size, void* d_ws, size_t ws_size,
                              hipStream_t stream) {
  const float* s    = (const float*)d_in[0];
  const float* z    = (const float*)d_in[1];
  const float* rot  = (const float*)d_in[2];
  const float* trn  = (const float*)d_in[3];
  const float* msk  = (const float*)d_in[4];
  const float* wq   = (const float*)d_in[5];
  const float* bq   = (const float*)d_in[6];
  const float* wkv  = (const float*)d_in[7];
  const float* bkv  = (const float*)d_in[8];
  const float* wqp  = (const float*)d_in[9];
  const float* bqp  = (const float*)d_in[10];
  const float* wkvp = (const float*)d_in[11];
  const float* bkvp = (const float*)d_in[12];
  const float* wb   = (const float*)d_in[13];
  const float* bb   = (const float*)d_in[14];
  const float* wout = (const float*)d_in[15];
  const float* bout = (const float*)d_in[16];
  const float* hwt  = (const float*)d_in[17];

  float* qws  = (float*)d_ws;                               // 196608 f32
  float* qgws = qws + 196608;                               // 147456 f32
  float* qnws = qgws + 147456;                              // 12288 f32
  float* qkpa = qnws + 12288;                               // 6291456 f32
  float* rawp = qkpa + 6291456;                             // 589824 f32
  unsigned short* vT    = (unsigned short*)(rawp + 589824); // 491520 u16
  unsigned short* kb2   = vT + 491520;                      // 491520 u16
  unsigned short* attnG = kb2 + 491520;                     // 6291456 u16
  unsigned short* feats = attnG + 6291456;                  // 2162688 u16
  unsigned short* woutT = feats + 2162688;                  // 811008 u16
  unsigned short* WT    = woutT + 811008;                   // 442368 u16
  float* out = (float*)d_out;

  k_prep<<<dim3(1224), dim3(256), 0, stream>>>(wout, woutT, wq, wkv, wqp, wkvp, WT);
  k_projG<<<dim3(16, 18), dim3(256), 0, stream>>>(s, WT, bq, bkv, bqp, bkvp,
                                                  qws, kb2, vT, rawp);
  k_points<<<dim3(256), dim3(512), 0, stream>>>(rawp, rot, trn, hwt, qgws, qnws, kb2, vT);
  k_qkpa<<<dim3(24, 8), dim3(256), 0, stream>>>(qws, qgws, qnws, hwt, msk, kb2, qkpa);
  k_attn<<<dim3(1024), dim3(512), 0, stream>>>(z, wb, bb, qkpa, attnG, feats);
  k_av<<<dim3(24, 8), dim3(256), 0, stream>>>(attnG, vT, rot, trn, feats);
  k_out<<<dim3(16, 12), dim3(256), 0, stream>>>(feats, woutT, bout, msk, out);
}

// Round 19
// 158.448 us; speedup vs baseline: 1.0017x; 1.0017x over previous
//
#include <hip/hip_runtime.h>

// IPA forward, MI355X. B=2,N=512,C_S=384,C_Z=128,H=12,D=16,PQ=4,PV=8,OUT_IN=2112.
// R17: k_attn z staging via __builtin_amdgcn_global_load_lds (width 16, fire-and-forget:
//      64KB in flight/block vs ~8KB with reg-dest loads). z held f32 in LDS (64KB, linear dest,
//      source pre-swizzle L^((L>>9&7)<<4)); bias MFMA + PC read f32+cvtpk. zbfc deleted;
//      attnbF 12 rows. Tail identical to R16 (MFMA proj pipeline).

typedef __attribute__((ext_vector_type(8))) short bf16x8;
typedef __attribute__((ext_vector_type(4))) float f32x4;
typedef __attribute__((ext_vector_type(4))) unsigned int u32x4;
typedef __attribute__((ext_vector_type(2))) unsigned int u32x2;

__device__ __forceinline__ unsigned short f2b(float f) {
  union { float f; unsigned int u; } x; x.f = f;
  unsigned int r = (x.u + 0x7FFFu + ((x.u >> 16) & 1u)) >> 16;
  return (unsigned short)r;
}
__device__ __forceinline__ float b2f(unsigned short u) {
  return __builtin_bit_cast(float, (unsigned int)u << 16);
}
__device__ __forceinline__ unsigned int cvtpk(float lo, float hi) {
  unsigned int r;
  asm("v_cvt_pk_bf16_f32 %0, %1, %2" : "=v"(r) : "v"(lo), "v"(hi));
  return r;
}
__device__ __forceinline__ void gload_lds16(const void* g, void* l) {
  __builtin_amdgcn_global_load_lds(
      (const __attribute__((address_space(1))) void*)g,
      (__attribute__((address_space(3))) void*)l, 16, 0, 0);
}
// concatenated projection weight element W[k][o]
__device__ __forceinline__ float wsrc(const float* wq, const float* wkv,
                                      const float* wqp, const float* wkvp, int k, int o) {
  if (o < 192)  return wq[k * 192 + o];
  if (o < 576)  return wkv[k * 384 + (o - 192)];
  if (o < 720)  return wqp[k * 144 + (o - 576)];
  return wkvp[k * 432 + (o - 720)];
}
__device__ __forceinline__ float bsrc(const float* bq, const float* bkv,
                                      const float* bqp, const float* bkvp, int o) {
  if (o < 192)  return bq[o];
  if (o < 576)  return bkv[o - 192];
  if (o < 720)  return bqp[o - 576];
  return bkvp[o - 720];
}

// ---------------- K0: k_prep — wout transpose (blocks 0..791) + W transpose (792..1223) ----------------
__global__ __launch_bounds__(256) void k_prep(
    const float* __restrict__ wout, unsigned short* __restrict__ woutT,
    const float* __restrict__ wq, const float* __restrict__ wkv,
    const float* __restrict__ wqp, const float* __restrict__ wkvp,
    unsigned short* __restrict__ WT) {
  __shared__ float tile[32][33];
  int tid = threadIdx.x;
  int tx = tid & 31, ty = tid >> 5;
  if (blockIdx.x < 792) {
    int bx = blockIdx.x;
    int kb = (bx % 66) * 32, cb = (bx / 66) * 32;
    #pragma unroll
    for (int r = ty; r < 32; r += 8) tile[r][tx] = wout[(size_t)(kb + r) * 384 + cb + tx];
    __syncthreads();
    #pragma unroll
    for (int r = ty; r < 32; r += 8) woutT[(size_t)(cb + r) * 2112 + kb + tx] = f2b(tile[tx][r]);
  } else {
    int bx = blockIdx.x - 792;
    int kb = (bx % 12) * 32, ob = (bx / 12) * 32;
    #pragma unroll
    for (int r = ty; r < 32; r += 8) tile[r][tx] = wsrc(wq, wkv, wqp, wkvp, kb + r, ob + tx);
    __syncthreads();
    #pragma unroll
    for (int r = ty; r < 32; r += 8) WT[(size_t)(ob + r) * 384 + kb + tx] = f2b(tile[tx][r]);
  }
}

// ---------------- K1: k_projG — C[1024 i][1152 o] = s @ W + b via MFMA, 64x64 tiles ----------------
__global__ __launch_bounds__(256) void k_projG(
    const float* __restrict__ s, const unsigned short* __restrict__ WT,
    const float* __restrict__ bq, const float* __restrict__ bkv,
    const float* __restrict__ bqp, const float* __restrict__ bkvp,
    float* __restrict__ qws,
    unsigned short* __restrict__ kb2, unsigned short* __restrict__ vT,
    float* __restrict__ rawp) {
  int tid = threadIdx.x;
  int wv = tid >> 6, l = tid & 63, lr = l & 15, lk = l >> 4;
  int wm = wv >> 1, wn = wv & 1;
  int i0 = blockIdx.x * 64, o0 = blockIdx.y * 64;
  f32x4 acc[2][2] = {};

  #pragma unroll 3
  for (int ks = 0; ks < 12; ks++) {
    int k0 = ks * 32;
    bf16x8 af[2], bf[2];
    #pragma unroll
    for (int mf = 0; mf < 2; mf++) {
      int i = i0 + wm * 32 + mf * 16 + lr;
      const float4* sp = (const float4*)(s + (size_t)i * 384 + k0);
      float4 a0 = sp[lk * 2], a1 = sp[lk * 2 + 1];
      u32x4 afp;
      afp[0] = cvtpk(a0.x, a0.y); afp[1] = cvtpk(a0.z, a0.w);
      afp[2] = cvtpk(a1.x, a1.y); afp[3] = cvtpk(a1.z, a1.w);
      af[mf] = __builtin_bit_cast(bf16x8, afp);
    }
    #pragma unroll
    for (int nf = 0; nf < 2; nf++) {
      int o = o0 + wn * 32 + nf * 16 + lr;
      bf[nf] = *(const bf16x8*)(WT + (size_t)o * 384 + k0 + lk * 8);
    }
    #pragma unroll
    for (int mf = 0; mf < 2; mf++)
      #pragma unroll
      for (int nf = 0; nf < 2; nf++)
        acc[mf][nf] = __builtin_amdgcn_mfma_f32_16x16x32_bf16(af[mf], bf[nf], acc[mf][nf], 0, 0, 0);
  }

  #pragma unroll
  for (int mf = 0; mf < 2; mf++) {
    #pragma unroll
    for (int nf = 0; nf < 2; nf++) {
      int o = o0 + wn * 32 + nf * 16 + lr;
      float bias = bsrc(bq, bkv, bqp, bkvp, o);
      #pragma unroll
      for (int reg = 0; reg < 4; reg++) {
        int i = i0 + wm * 32 + mf * 16 + lk * 4 + reg;
        float v = acc[mf][nf][reg] + bias;
        int b2 = i >> 9, jj = i & 511;
        if (o < 192) {
          qws[(size_t)i * 192 + o] = v;
        } else if (o < 576) {
          int c = o - 192, h = c >> 5, e = c & 31;
          if (e < 16)
            kb2[(((size_t)b2 * 12 + h) * 512 + jj) * 40 + e] = f2b(v);
          else
            vT[((size_t)b2 * 480 + h * 16 + (e - 16)) * 512 + jj] = f2b(v);
        } else {
          rawp[(size_t)i * 576 + (o - 576)] = v;
        }
      }
    }
  }
}

// ---------------- K2: k_points — rotation/norm epilogue from rawp ----------------
__global__ __launch_bounds__(512) void k_points(
    const float* __restrict__ rawp,
    const float* __restrict__ rot, const float* __restrict__ trn,
    const float* __restrict__ hwt,
    float* __restrict__ qgws, float* __restrict__ qnws,
    unsigned short* __restrict__ kb2, unsigned short* __restrict__ vT) {
  __shared__ float praw[4][576];
  int tid = threadIdx.x;
  int row0 = blockIdx.x * 4;

  for (int idx = tid; idx < 2304; idx += 512)
    praw[idx / 576][idx % 576] = rawp[(size_t)row0 * 576 + idx];
  __syncthreads();

  for (int idx = tid; idx < 768; idx += 512) {
    int r = idx / 192, p = idx % 192;
    int bi = row0 + r;
    int bb2 = bi >> 9, jj = bi & 511;
    const float* Rm = rot + (size_t)bi * 9;
    const float* tv = trn + (size_t)bi * 3;
    float x, y, z;
    if (p < 48) { x = praw[r][p]; y = praw[r][48 + p]; z = praw[r][96 + p]; }
    else { int q = p - 48; x = praw[r][144 + q]; y = praw[r][288 + q]; z = praw[r][432 + q]; }
    float gx = Rm[0] * x + Rm[1] * y + Rm[2] * z + tv[0];
    float gy = Rm[3] * x + Rm[4] * y + Rm[5] * z + tv[1];
    float gz = Rm[6] * x + Rm[7] * y + Rm[8] * z + tv[2];
    if (p < 48) {
      float* dst = qgws + (size_t)bi * 144 + p * 3;
      dst[0] = gx; dst[1] = gy; dst[2] = gz;
    } else {
      int q12 = p - 48; int h = q12 / 12, qq = q12 % 12;
      if (qq < 4) {
        size_t base = (((size_t)bb2 * 12 + h) * 512 + jj) * 40 + 16 + qq * 3;
        kb2[base + 0] = f2b(gx); kb2[base + 1] = f2b(gy); kb2[base + 2] = f2b(gz);
      } else {
        size_t base = ((size_t)bb2 * 480 + 192 + h * 24 + (qq - 4) * 3) * 512 + jj;
        vT[base] = f2b(gx); vT[base + 512] = f2b(gy); vT[base + 1024] = f2b(gz);
      }
    }
  }

  if (tid < 48) {
    int r = tid / 12, h = tid % 12;
    int bi = row0 + r;
    int bb2 = bi >> 9, jj = bi & 511;
    const float* Rm = rot + (size_t)bi * 9;
    const float* tv = trn + (size_t)bi * 3;
    float hw = 0.5f * logf(1.0f + __expf(hwt[h])) * 0.13608276348795434f;
    float qn = 0.f, kn = 0.f;
    #pragma unroll
    for (int qq = 0; qq < 4; qq++) {
      {
        int p = h * 4 + qq;
        float x = praw[r][p], y = praw[r][48 + p], z = praw[r][96 + p];
        float gx = Rm[0]*x + Rm[1]*y + Rm[2]*z + tv[0];
        float gy = Rm[3]*x + Rm[4]*y + Rm[5]*z + tv[1];
        float gz = Rm[6]*x + Rm[7]*y + Rm[8]*z + tv[2];
        qn += gx*gx + gy*gy + gz*gz;
      }
      {
        int q = h * 12 + qq;
        float x = praw[r][144 + q], y = praw[r][288 + q], z = praw[r][432 + q];
        float gx = Rm[0]*x + Rm[1]*y + Rm[2]*z + tv[0];
        float gy = Rm[3]*x + Rm[4]*y + Rm[5]*z + tv[1];
        float gz = Rm[6]*x + Rm[7]*y + Rm[8]*z + tv[2];
        kn += gx*gx + gy*gy + gz*gz;
      }
    }
    qnws[(size_t)bi * 12 + h] = qn;
    float pr = -hw * kn;
    unsigned short hi = f2b(pr);
    unsigned short lo = f2b(pr - b2f(hi));
    size_t base = (((size_t)bb2 * 12 + h) * 512 + jj) * 40;
    kb2[base + 28] = hi; kb2[base + 29] = lo;
    kb2[base + 30] = 0x3F80; kb2[base + 31] = 0x3F80;
  }
}

// ---------------- K3: qkpa per-(b,h) GEMM, 64-i chunks (192 blocks) ----------------
__global__ __launch_bounds__(256) void k_qkpa(
    const float* __restrict__ qws, const float* __restrict__ qgws,
    const float* __restrict__ qnws, const float* __restrict__ hwt,
    const float* __restrict__ mrow,
    const unsigned short* __restrict__ kb2,
    float* __restrict__ qkpa) {
  __shared__ unsigned short aq[64 * 40];
  __shared__ float mI[64];
  __shared__ float mJ[512];
  int bh = blockIdx.x;
  int b = bh / 12, h = bh - b * 12;
  int i0 = blockIdx.y * 64;
  int tid = threadIdx.x;
  float hw = 0.5f * logf(1.0f + __expf(hwt[h])) * 0.13608276348795434f;

  for (int idx = tid; idx < 512; idx += 256) mJ[idx] = mrow[b * 512 + idx];
  if (tid < 64) mI[tid] = mrow[b * 512 + i0 + tid];
  {
    int r = tid >> 2, c0 = (tid & 3) * 10;
    size_t gi = (size_t)b * 512 + i0 + r;
    const float* qr = qws + gi * 192 + h * 16;
    const float* gr = qgws + gi * 144 + h * 12;
    float pr = -hw * qnws[gi * 12 + h];
    unsigned short hi = f2b(pr);
    unsigned short lo = f2b(pr - b2f(hi));
    for (int c = c0; c < c0 + 10; c++) {
      unsigned short v;
      if (c < 16)      v = f2b(0.14433756729740643f * qr[c]);
      else if (c < 28) v = f2b(2.0f * hw * gr[c - 16]);
      else if (c < 30) v = 0x3F80;
      else if (c == 30) v = hi;
      else              v = lo;
      aq[r * 40 + c] = v;
    }
  }
  __syncthreads();

  int w = tid >> 6, l = tid & 63, lr = l & 15, lk = l >> 4;
  int n0 = w * 128;
  bf16x8 afr[4];
  #pragma unroll
  for (int mf = 0; mf < 4; mf++)
    afr[mf] = *(const bf16x8*)&aq[(mf * 16 + lr) * 40 + lk * 8];
  const unsigned short* kbb = kb2 + (size_t)bh * 512 * 40;
  #pragma unroll 2
  for (int nf = 0; nf < 8; nf++) {
    int j = n0 + nf * 16 + lr;
    float mjv = mJ[j];
    bf16x8 bfr = *(const bf16x8*)(kbb + (size_t)j * 40 + lk * 8);
    #pragma unroll
    for (int mf = 0; mf < 4; mf++) {
      f32x4 acc = {0.f, 0.f, 0.f, 0.f};
      acc = __builtin_amdgcn_mfma_f32_16x16x32_bf16(afr[mf], bfr, acc, 0, 0, 0);
      #pragma unroll
      for (int r = 0; r < 4; r++) {
        int il = mf * 16 + lk * 4 + r;
        int i = i0 + il;
        float val = acc[r] + 100000.0f * (mI[il] * mjv - 1.0f);
        qkpa[((size_t)(b * 512 + i) * 12 + h) * 512 + j] = val;
      }
    }
  }
}

// ---------------- K4: fused per (b,i), chunked flash-style + global_load_lds z staging ----------------
__global__ __launch_bounds__(512, 1) void k_attn(
    const float* __restrict__ z,
    const float* __restrict__ wb, const float* __restrict__ bb,
    const float* __restrict__ qkpa,
    unsigned short* __restrict__ attnG,
    unsigned short* __restrict__ feats) {
  __shared__ __align__(16) char zf32c[65536];            // [128 j][128 c] f32, src-preswizzled
  __shared__ __align__(16) unsigned short attnbF[6144];  // [12 h][512 j] bf16 swizzled
  __shared__ __align__(16) float logitsC[12][132];
  __shared__ unsigned short wbT[1536];                   // [12 h][128 c] bf16
  __shared__ float bbl[16];
  __shared__ float mrun[12], lrun[12], frh[16], m_used[12][4], rinv[16];

  int tid = threadIdx.x;
  int bi = blockIdx.x;
  int b = bi >> 9;
  const char* zbaseB = (const char*)(z + (size_t)bi * 65536);
  int wv = tid >> 6, l = tid & 63, lr = l & 15, lk = l >> 4;

  if (tid < 16) bbl[tid] = (tid < 12) ? bb[tid] : 0.0f;
  else if (tid >= 16 && tid < 28) { mrun[tid - 16] = -1e30f; lrun[tid - 16] = 0.f; }
  else if (tid >= 28 && tid < 44) frh[tid - 28] = 1.0f;
  for (int idx = tid; idx < 1536; idx += 512) {
    int h = idx >> 7, c = idx & 127;
    wbT[h * 128 + c] = f2b(wb[c * 12 + h]);
  }
  __syncthreads();

  int hcl = (lr < 12) ? lr : 0;   // clamp for B-frag reads (cols >=12 discarded)
  bf16x8 bfrag[4];
  #pragma unroll
  for (int kc = 0; kc < 4; kc++)
    bfrag[kc] = *(const bf16x8*)(wbT + hcl * 128 + kc * 32 + lk * 8);

  f32x4 accPC = {0.f, 0.f, 0.f, 0.f};
  int c0 = wv * 16;
  int ldsbase = wv * 1024 + l * 16;   // per-thread linear slot within 8KB stripe

  #pragma unroll 1
  for (int ch = 0; ch < 4; ch++) {
    int j0 = ch * 128;
    // stage: 8 x global_load_lds (16B), linear LDS dest, pre-swizzled global src
    {
      const char* gchunk = zbaseB + (size_t)j0 * 512;
      #pragma unroll
      for (int q = 0; q < 8; q++) {
        int L = q * 8192 + ldsbase;
        int src = L ^ (((L >> 9) & 7) << 4);
        gload_lds16(gchunk + src, zf32c + (q * 8192 + wv * 1024));
      }
    }
    __syncthreads();   // drains vmcnt -> chunk resident

    // bias MFMA: per wave one 16-j tile; A = z rows (f32 from LDS, cvtpk), B = wbT
    {
      int jb = wv * 16 + lr;
      int sw = (jb & 7) << 4;
      f32x4 acc = {0.f, 0.f, 0.f, 0.f};
      #pragma unroll
      for (int kc = 0; kc < 4; kc++) {
        int bbyte = jb * 512 + (kc * 32 + lk * 8) * 4;
        float4 a0 = *(const float4*)(zf32c + (bbyte ^ sw));
        float4 a1 = *(const float4*)(zf32c + ((bbyte + 16) ^ sw));
        u32x4 af;
        af[0] = cvtpk(a0.x, a0.y); af[1] = cvtpk(a0.z, a0.w);
        af[2] = cvtpk(a1.x, a1.y); af[3] = cvtpk(a1.z, a1.w);
        acc = __builtin_amdgcn_mfma_f32_16x16x32_bf16(__builtin_bit_cast(bf16x8, af), bfrag[kc], acc, 0, 0, 0);
      }
      if (lr < 12) {
        #pragma unroll
        for (int reg = 0; reg < 4; reg++)
          logitsC[lr][wv * 16 + lk * 4 + reg] = 0.5773502691896258f * (acc[reg] + bbl[lr]);
      }
    }
    __syncthreads();

    // PBc: qkpa add + online softmax -> attnbF (chunk-scaled exp, bf16)
    if (tid < 384) {
      int h = tid >> 5, g = tid & 31;
      float4 v = *(const float4*)&logitsC[h][g * 4];
      float4 q4 = *(const float4*)(qkpa + (size_t)bi * 6144 + h * 512 + j0 + g * 4);
      v.x += q4.x; v.y += q4.y; v.z += q4.z; v.w += q4.w;
      float pmx = fmaxf(fmaxf(v.x, v.y), fmaxf(v.z, v.w));
      #pragma unroll
      for (int off = 16; off > 0; off >>= 1) pmx = fmaxf(pmx, __shfl_xor(pmx, off, 32));
      float m_old = mrun[h];
      float m_new = fmaxf(m_old, pmx);
      float fr = __expf(m_old - m_new);
      float4 e;
      e.x = __expf(v.x - m_new); e.y = __expf(v.y - m_new);
      e.z = __expf(v.z - m_new); e.w = __expf(v.w - m_new);
      float sm = e.x + e.y + e.z + e.w;
      #pragma unroll
      for (int off = 16; off > 0; off >>= 1) sm += __shfl_xor(sm, off, 32);
      if (g == 0) {
        lrun[h] = lrun[h] * fr + sm;
        mrun[h] = m_new;
        m_used[h][ch] = m_new;
        frh[h] = fr;
      }
      u32x2 ob;
      ob[0] = cvtpk(e.x, e.y); ob[1] = cvtpk(e.z, e.w);
      int j4 = j0 + g * 4;
      int byte = (h * 1024 + j4 * 2) ^ ((h & 7) << 4);
      *(u32x2*)((char*)attnbF + byte) = ob;
    }
    __syncthreads();

    // PCc: out_pair accumulate. A = z c-rows (scalar f32 from LDS, cvtpk), B = attn rows.
    {
      float fr = frh[hcl];
      accPC[0] *= fr; accPC[1] *= fr; accPC[2] *= fr; accPC[3] *= fr;
      #pragma unroll
      for (int jt = 0; jt < 4; jt++) {
        u32x4 afp;
        #pragma unroll
        for (int e2 = 0; e2 < 4; e2++) {
          int ja = jt * 32 + lk * 8 + e2 * 2;
          int jb2 = ja + 1;
          float f1 = *(const float*)(zf32c + ((ja * 512 + (c0 + lr) * 4) ^ ((ja & 7) << 4)));
          float f2 = *(const float*)(zf32c + ((jb2 * 512 + (c0 + lr) * 4) ^ ((jb2 & 7) << 4)));
          afp[e2] = cvtpk(f1, f2);
        }
        int pb = (hcl * 1024 + (j0 + jt * 32 + lk * 8) * 2) ^ ((hcl & 7) << 4);
        bf16x8 pfrag = *(const bf16x8*)((const char*)attnbF + pb);
        accPC = __builtin_amdgcn_mfma_f32_16x16x32_bf16(__builtin_bit_cast(bf16x8, afp), pfrag, accPC, 0, 0, 0);
      }
    }
    __syncthreads();
  }

  if (tid < 16) rinv[tid] = (tid < 12) ? (1.0f / lrun[tid]) : 0.0f;
  __syncthreads();

  size_t fb = (size_t)bi * 2112;

  // attnG write with global fixup exp(m_used - m_final) * rinv
  if (tid < 384) {
    int h = tid >> 5, g = tid & 31;
    float rn = rinv[h];
    float mf = mrun[h];
    unsigned short* gout = attnG + (((size_t)(b * 12 + h) * 512) + (bi & 511)) * 512;
    #pragma unroll
    for (int ch = 0; ch < 4; ch++) {
      float sc = __expf(m_used[h][ch] - mf) * rn;
      int j4 = ch * 128 + g * 4;
      int byte = (h * 1024 + j4 * 2) ^ ((h & 7) << 4);
      u32x2 ob = *(const u32x2*)((const char*)attnbF + byte);
      float f0 = b2f((unsigned short)(ob[0] & 0xffffu)) * sc;
      float f1 = b2f((unsigned short)(ob[0] >> 16)) * sc;
      float f2 = b2f((unsigned short)(ob[1] & 0xffffu)) * sc;
      float f3 = b2f((unsigned short)(ob[1] >> 16)) * sc;
      u32x2 ow;
      ow[0] = cvtpk(f0, f1); ow[1] = cvtpk(f2, f3);
      *(u32x2*)(gout + j4) = ow;
    }
  }

  // out_pair write: h = lr, c = c0 + lk*4 + reg
  if (lr < 12) {
    float rn = rinv[lr];
    u32x2 ow;
    ow[0] = cvtpk(accPC[0] * rn, accPC[1] * rn);
    ow[1] = cvtpk(accPC[2] * rn, accPC[3] * rn);
    *(u32x2*)&feats[fb + 576 + lr * 128 + c0 + lk * 4] = ow;
  }
}

// ---------------- K5: [out_scalar | rpg] per-(b,h) GEMM, 64-i chunks (192 blocks) ----------------
__global__ __launch_bounds__(256) void k_av(
    const unsigned short* __restrict__ attnG, const unsigned short* __restrict__ vT,
    const float* __restrict__ rot, const float* __restrict__ trn,
    unsigned short* __restrict__ feats) {
  __shared__ float sc[64 * 24];
  __shared__ float rotL[64 * 9];
  __shared__ float trnL[64 * 3];
  int bh = blockIdx.x;
  int b = bh / 12, h = bh - b * 12;
  int i0 = blockIdx.y * 64;
  int tid = threadIdx.x;

  for (int idx = tid; idx < 576; idx += 256) rotL[idx] = rot[((size_t)b * 512 + i0) * 9 + idx];
  for (int idx = tid; idx < 192; idx += 256) trnL[idx] = trn[((size_t)b * 512 + i0) * 3 + idx];

  int w = tid >> 6, l = tid & 63, lr = l & 15, lk = l >> 4;
  int iw = w * 16;
  const unsigned short* Abase = attnG + ((size_t)bh * 512 + i0 + iw) * 512;
  const unsigned short* vTb = vT + (size_t)b * 480 * 512;
  int cm[3];
  #pragma unroll
  for (int nf = 0; nf < 3; nf++) {
    int c = nf * 16 + lr;
    cm[nf] = (c < 16) ? (h * 16 + c) : (c < 40 ? 192 + h * 24 + (c - 16) : 0);
  }
  f32x4 acc[3] = {};
  #pragma unroll 2
  for (int jb = 0; jb < 512; jb += 32) {
    bf16x8 a0 = *(const bf16x8*)(Abase + (size_t)lr * 512 + jb + lk * 8);
    #pragma unroll
    for (int nf = 0; nf < 3; nf++) {
      bf16x8 bfr = *(const bf16x8*)(vTb + (size_t)cm[nf] * 512 + jb + lk * 8);
      acc[nf] = __builtin_amdgcn_mfma_f32_16x16x32_bf16(a0, bfr, acc[nf], 0, 0, 0);
    }
  }
  #pragma unroll
  for (int nf = 0; nf < 3; nf++) {
    int c = nf * 16 + lr;
    #pragma unroll
    for (int r = 0; r < 4; r++) {
      int il = iw + lk * 4 + r;
      float v = acc[nf][r];
      if (c < 16) feats[(size_t)(b * 512 + i0 + il) * 2112 + h * 16 + c] = f2b(v);
      else if (c < 40) sc[il * 24 + (c - 16)] = v;
    }
  }
  __syncthreads();
  #pragma unroll
  for (int k2 = 0; k2 < 2; k2++) {
    int itm = tid + k2 * 256;
    int il = itm >> 3, pv = itm & 7;
    float gx = sc[il * 24 + pv * 3 + 0] - trnL[il * 3 + 0];
    float gy = sc[il * 24 + pv * 3 + 1] - trnL[il * 3 + 1];
    float gz = sc[il * 24 + pv * 3 + 2] - trnL[il * 3 + 2];
    const float* R = &rotL[il * 9];
    float lx = R[0] * gx + R[3] * gy + R[6] * gz;
    float ly = R[1] * gx + R[4] * gy + R[7] * gz;
    float lz = R[2] * gx + R[5] * gy + R[8] * gz;
    size_t fb = (size_t)(b * 512 + i0 + il) * 2112;
    feats[fb + 192 + h * 8 + pv] = f2b(lx);
    feats[fb + 288 + h * 8 + pv] = f2b(ly);
    feats[fb + 384 + h * 8 + pv] = f2b(lz);
    feats[fb + 480 + h * 8 + pv] = f2b(sqrtf(lx * lx + ly * ly + lz * lz + 1e-8f));
  }
}

// ---------------- K6: out = (feats @ wout + bout) * mask, 64x32 tiles ----------------
__global__ __launch_bounds__(256) void k_out(const unsigned short* __restrict__ feats,
                                             const unsigned short* __restrict__ woutT,
                                             const float* __restrict__ bout,
                                             const float* __restrict__ mrow,
                                             float* __restrict__ out) {
  __shared__ unsigned short At[2048];
  __shared__ unsigned short Bt[1024];
  int m0 = blockIdx.x * 64, n0 = blockIdx.y * 32;
  int tid = threadIdx.x;
  int wv = tid >> 6, l = tid & 63, lr = l & 15, lk = l >> 4;
  int wm = wv >> 1, wn = wv & 1;
  f32x4 acc[2] = {};
  int sr = tid >> 2, sq = tid & 3;
  const char* fbase = (const char*)feats + (size_t)(m0 + sr) * 4224 + sq * 16;
  int swA = (sr * 64 + sq * 16) ^ ((sr & 7) << 4);
  int rb = tid >> 2, qb = tid & 3;
  const char* bbase = (const char*)woutT + (size_t)(n0 + rb) * 4224 + qb * 16;
  int swB = (rb * 64 + qb * 16) ^ ((rb & 7) << 4);

  uint4 av = *(const uint4*)(fbase);
  uint4 bv = {0, 0, 0, 0};
  if (tid < 128) bv = *(const uint4*)(bbase);
  for (int k0 = 0; k0 < 2112; k0 += 32) {
    __syncthreads();
    *(uint4*)((char*)At + swA) = av;
    if (tid < 128) *(uint4*)((char*)Bt + swB) = bv;
    __syncthreads();
    if (k0 + 32 < 2112) {
      av = *(const uint4*)(fbase + (size_t)(k0 + 32) * 2);
      if (tid < 128) bv = *(const uint4*)(bbase + (size_t)(k0 + 32) * 2);
    }
    bf16x8 af[2], bfv;
    #pragma unroll
    for (int mt = 0; mt < 2; mt++) {
      int row = wm * 32 + mt * 16 + lr;
      af[mt] = *(const bf16x8*)((const char*)At + ((row * 64 + lk * 16) ^ ((row & 7) << 4)));
    }
    {
      int row = wn * 16 + lr;
      bfv = *(const bf16x8*)((const char*)Bt + ((row * 64 + lk * 16) ^ ((row & 7) << 4)));
    }
    #pragma unroll
    for (int mt = 0; mt < 2; mt++)
      acc[mt] = __builtin_amdgcn_mfma_f32_16x16x32_bf16(af[mt], bfv, acc[mt], 0, 0, 0);
  }

  #pragma unroll
  for (int mt = 0; mt < 2; mt++) {
    int nc = n0 + wn * 16 + lr;
    float bo = bout[nc];
    #pragma unroll
    for (int reg = 0; reg < 4; reg++) {
      int rowg = m0 + wm * 32 + mt * 16 + lk * 4 + reg;
      out[(size_t)rowg * 384 + nc] = (acc[mt][reg] + bo) * mrow[rowg];
    }
  }
}

extern "C" void kernel_launch(void* const* d_in, const int* in_sizes, int n_in,
                              void* d_out, int out_size, void* d_ws, size_t ws_size,
                              hipStream_t stream) {
  const float* s    = (const float*)d_in[0];
  const float* z    = (const float*)d_in[1];
  const float* rot  = (const float*)d_in[2];
  const float* trn  = (const float*)d_in[3];
  const float* msk  = (const float*)d_in[4];
  const float* wq   = (const float*)d_in[5];
  const float* bq   = (const float*)d_in[6];
  const float* wkv  = (const float*)d_in[7];
  const float* bkv  = (const float*)d_in[8];
  const float* wqp  = (const float*)d_in[9];
  const float* bqp  = (const float*)d_in[10];
  const float* wkvp = (const float*)d_in[11];
  const float* bkvp = (const float*)d_in[12];
  const float* wb   = (const float*)d_in[13];
  const float* bb   = (const float*)d_in[14];
  const float* wout = (const float*)d_in[15];
  const float* bout = (const float*)d_in[16];
  const float* hwt  = (const float*)d_in[17];

  float* qws  = (float*)d_ws;                               // 196608 f32
  float* qgws = qws + 196608;                               // 147456 f32
  float* qnws = qgws + 147456;                              // 12288 f32
  float* qkpa = qnws + 12288;                               // 6291456 f32
  float* rawp = qkpa + 6291456;                             // 589824 f32
  unsigned short* vT    = (unsigned short*)(rawp + 589824); // 491520 u16
  unsigned short* kb2   = vT + 491520;                      // 491520 u16
  unsigned short* attnG = kb2 + 491520;                     // 6291456 u16
  unsigned short* feats = attnG + 6291456;                  // 2162688 u16
  unsigned short* woutT = feats + 2162688;                  // 811008 u16
  unsigned short* WT    = woutT + 811008;                   // 442368 u16
  float* out = (float*)d_out;

  k_prep<<<dim3(1224), dim3(256), 0, stream>>>(wout, woutT, wq, wkv, wqp, wkvp, WT);
  k_projG<<<dim3(16, 18), dim3(256), 0, stream>>>(s, WT, bq, bkv, bqp, bkvp,
                                                  qws, kb2, vT, rawp);
  k_points<<<dim3(256), dim3(512), 0, stream>>>(rawp, rot, trn, hwt, qgws, qnws, kb2, vT);
  k_qkpa<<<dim3(24, 8), dim3(256), 0, stream>>>(qws, qgws, qnws, hwt, msk, kb2, qkpa);
  k_attn<<<dim3(1024), dim3(512), 0, stream>>>(z, wb, bb, qkpa, attnG, feats);
  k_av<<<dim3(24, 8), dim3(256), 0, stream>>>(attnG, vT, rot, trn, feats);
  k_out<<<dim3(16, 12), dim3(256), 0, stream>>>(feats, woutT, bout, msk, out);
}

// Round 20
// 135.418 us; speedup vs baseline: 1.1720x; 1.1701x over previous
//
#include <hip/hip_runtime.h>

// IPA forward, MI355X. B=2,N=512,C_S=384,C_Z=128,H=12,D=16,PQ=4,PV=8,OUT_IN=2112.
// R19: k_attn = exact R16/R12 revert (best: 139.8; R17 global_load_lds regressed).
//      qkpa stored as f16 (24->12 MB round-trip), clamped at -30000 for mask safety.
//      Everything else identical to R16.

typedef __attribute__((ext_vector_type(8))) short bf16x8;
typedef __attribute__((ext_vector_type(4))) float f32x4;
typedef __attribute__((ext_vector_type(4))) unsigned int u32x4;
typedef __attribute__((ext_vector_type(2))) unsigned int u32x2;

__device__ __forceinline__ unsigned short f2b(float f) {
  union { float f; unsigned int u; } x; x.f = f;
  unsigned int r = (x.u + 0x7FFFu + ((x.u >> 16) & 1u)) >> 16;
  return (unsigned short)r;
}
__device__ __forceinline__ float b2f(unsigned short u) {
  return __builtin_bit_cast(float, (unsigned int)u << 16);
}
__device__ __forceinline__ unsigned int cvtpk(float lo, float hi) {
  unsigned int r;
  asm("v_cvt_pk_bf16_f32 %0, %1, %2" : "=v"(r) : "v"(lo), "v"(hi));
  return r;
}
__device__ __forceinline__ unsigned short f2h(float f) {
  return __builtin_bit_cast(unsigned short, (_Float16)f);
}
__device__ __forceinline__ float h2f(unsigned short u) {
  return (float)__builtin_bit_cast(_Float16, u);
}
// chunk z tile byte address: [128 c][128 j] bf16, swizzled within 256B row.
__device__ __forceinline__ int zaddrc(int c, int j) {
  return (((c << 8) + (j << 1)) ^ ((c & 7) << 4) ^ (((c >> 3) & 7) << 5));
}
// concatenated projection weight element W[k][o]
__device__ __forceinline__ float wsrc(const float* wq, const float* wkv,
                                      const float* wqp, const float* wkvp, int k, int o) {
  if (o < 192)  return wq[k * 192 + o];
  if (o < 576)  return wkv[k * 384 + (o - 192)];
  if (o < 720)  return wqp[k * 144 + (o - 576)];
  return wkvp[k * 432 + (o - 720)];
}
__device__ __forceinline__ float bsrc(const float* bq, const float* bkv,
                                      const float* bqp, const float* bkvp, int o) {
  if (o < 192)  return bq[o];
  if (o < 576)  return bkv[o - 192];
  if (o < 720)  return bqp[o - 576];
  return bkvp[o - 720];
}

// ---------------- K0: k_prep — wout transpose (blocks 0..791) + W transpose (792..1223) ----------------
__global__ __launch_bounds__(256) void k_prep(
    const float* __restrict__ wout, unsigned short* __restrict__ woutT,
    const float* __restrict__ wq, const float* __restrict__ wkv,
    const float* __restrict__ wqp, const float* __restrict__ wkvp,
    unsigned short* __restrict__ WT) {
  __shared__ float tile[32][33];
  int tid = threadIdx.x;
  int tx = tid & 31, ty = tid >> 5;
  if (blockIdx.x < 792) {
    int bx = blockIdx.x;
    int kb = (bx % 66) * 32, cb = (bx / 66) * 32;
    #pragma unroll
    for (int r = ty; r < 32; r += 8) tile[r][tx] = wout[(size_t)(kb + r) * 384 + cb + tx];
    __syncthreads();
    #pragma unroll
    for (int r = ty; r < 32; r += 8) woutT[(size_t)(cb + r) * 2112 + kb + tx] = f2b(tile[tx][r]);
  } else {
    int bx = blockIdx.x - 792;
    int kb = (bx % 12) * 32, ob = (bx / 12) * 32;
    #pragma unroll
    for (int r = ty; r < 32; r += 8) tile[r][tx] = wsrc(wq, wkv, wqp, wkvp, kb + r, ob + tx);
    __syncthreads();
    #pragma unroll
    for (int r = ty; r < 32; r += 8) WT[(size_t)(ob + r) * 384 + kb + tx] = f2b(tile[tx][r]);
  }
}

// ---------------- K1: k_projG — C[1024 i][1152 o] = s @ W + b via MFMA, 64x64 tiles ----------------
__global__ __launch_bounds__(256) void k_projG(
    const float* __restrict__ s, const unsigned short* __restrict__ WT,
    const float* __restrict__ bq, const float* __restrict__ bkv,
    const float* __restrict__ bqp, const float* __restrict__ bkvp,
    float* __restrict__ qws,
    unsigned short* __restrict__ kb2, unsigned short* __restrict__ vT,
    float* __restrict__ rawp) {
  int tid = threadIdx.x;
  int wv = tid >> 6, l = tid & 63, lr = l & 15, lk = l >> 4;
  int wm = wv >> 1, wn = wv & 1;
  int i0 = blockIdx.x * 64, o0 = blockIdx.y * 64;
  f32x4 acc[2][2] = {};

  #pragma unroll 3
  for (int ks = 0; ks < 12; ks++) {
    int k0 = ks * 32;
    bf16x8 af[2], bf[2];
    #pragma unroll
    for (int mf = 0; mf < 2; mf++) {
      int i = i0 + wm * 32 + mf * 16 + lr;
      const float4* sp = (const float4*)(s + (size_t)i * 384 + k0);
      float4 a0 = sp[lk * 2], a1 = sp[lk * 2 + 1];
      u32x4 afp;
      afp[0] = cvtpk(a0.x, a0.y); afp[1] = cvtpk(a0.z, a0.w);
      afp[2] = cvtpk(a1.x, a1.y); afp[3] = cvtpk(a1.z, a1.w);
      af[mf] = __builtin_bit_cast(bf16x8, afp);
    }
    #pragma unroll
    for (int nf = 0; nf < 2; nf++) {
      int o = o0 + wn * 32 + nf * 16 + lr;
      bf[nf] = *(const bf16x8*)(WT + (size_t)o * 384 + k0 + lk * 8);
    }
    #pragma unroll
    for (int mf = 0; mf < 2; mf++)
      #pragma unroll
      for (int nf = 0; nf < 2; nf++)
        acc[mf][nf] = __builtin_amdgcn_mfma_f32_16x16x32_bf16(af[mf], bf[nf], acc[mf][nf], 0, 0, 0);
  }

  #pragma unroll
  for (int mf = 0; mf < 2; mf++) {
    #pragma unroll
    for (int nf = 0; nf < 2; nf++) {
      int o = o0 + wn * 32 + nf * 16 + lr;
      float bias = bsrc(bq, bkv, bqp, bkvp, o);
      #pragma unroll
      for (int reg = 0; reg < 4; reg++) {
        int i = i0 + wm * 32 + mf * 16 + lk * 4 + reg;
        float v = acc[mf][nf][reg] + bias;
        int b2 = i >> 9, jj = i & 511;
        if (o < 192) {
          qws[(size_t)i * 192 + o] = v;
        } else if (o < 576) {
          int c = o - 192, h = c >> 5, e = c & 31;
          if (e < 16)
            kb2[(((size_t)b2 * 12 + h) * 512 + jj) * 40 + e] = f2b(v);
          else
            vT[((size_t)b2 * 480 + h * 16 + (e - 16)) * 512 + jj] = f2b(v);
        } else {
          rawp[(size_t)i * 576 + (o - 576)] = v;
        }
      }
    }
  }
}

// ---------------- K2: k_points — rotation/norm epilogue from rawp ----------------
__global__ __launch_bounds__(512) void k_points(
    const float* __restrict__ rawp,
    const float* __restrict__ rot, const float* __restrict__ trn,
    const float* __restrict__ hwt,
    float* __restrict__ qgws, float* __restrict__ qnws,
    unsigned short* __restrict__ kb2, unsigned short* __restrict__ vT) {
  __shared__ float praw[4][576];
  int tid = threadIdx.x;
  int row0 = blockIdx.x * 4;

  for (int idx = tid; idx < 2304; idx += 512)
    praw[idx / 576][idx % 576] = rawp[(size_t)row0 * 576 + idx];
  __syncthreads();

  for (int idx = tid; idx < 768; idx += 512) {
    int r = idx / 192, p = idx % 192;
    int bi = row0 + r;
    int bb2 = bi >> 9, jj = bi & 511;
    const float* Rm = rot + (size_t)bi * 9;
    const float* tv = trn + (size_t)bi * 3;
    float x, y, z;
    if (p < 48) { x = praw[r][p]; y = praw[r][48 + p]; z = praw[r][96 + p]; }
    else { int q = p - 48; x = praw[r][144 + q]; y = praw[r][288 + q]; z = praw[r][432 + q]; }
    float gx = Rm[0] * x + Rm[1] * y + Rm[2] * z + tv[0];
    float gy = Rm[3] * x + Rm[4] * y + Rm[5] * z + tv[1];
    float gz = Rm[6] * x + Rm[7] * y + Rm[8] * z + tv[2];
    if (p < 48) {
      float* dst = qgws + (size_t)bi * 144 + p * 3;
      dst[0] = gx; dst[1] = gy; dst[2] = gz;
    } else {
      int q12 = p - 48; int h = q12 / 12, qq = q12 % 12;
      if (qq < 4) {
        size_t base = (((size_t)bb2 * 12 + h) * 512 + jj) * 40 + 16 + qq * 3;
        kb2[base + 0] = f2b(gx); kb2[base + 1] = f2b(gy); kb2[base + 2] = f2b(gz);
      } else {
        size_t base = ((size_t)bb2 * 480 + 192 + h * 24 + (qq - 4) * 3) * 512 + jj;
        vT[base] = f2b(gx); vT[base + 512] = f2b(gy); vT[base + 1024] = f2b(gz);
      }
    }
  }

  if (tid < 48) {
    int r = tid / 12, h = tid % 12;
    int bi = row0 + r;
    int bb2 = bi >> 9, jj = bi & 511;
    const float* Rm = rot + (size_t)bi * 9;
    const float* tv = trn + (size_t)bi * 3;
    float hw = 0.5f * logf(1.0f + __expf(hwt[h])) * 0.13608276348795434f;
    float qn = 0.f, kn = 0.f;
    #pragma unroll
    for (int qq = 0; qq < 4; qq++) {
      {
        int p = h * 4 + qq;
        float x = praw[r][p], y = praw[r][48 + p], z = praw[r][96 + p];
        float gx = Rm[0]*x + Rm[1]*y + Rm[2]*z + tv[0];
        float gy = Rm[3]*x + Rm[4]*y + Rm[5]*z + tv[1];
        float gz = Rm[6]*x + Rm[7]*y + Rm[8]*z + tv[2];
        qn += gx*gx + gy*gy + gz*gz;
      }
      {
        int q = h * 12 + qq;
        float x = praw[r][144 + q], y = praw[r][288 + q], z = praw[r][432 + q];
        float gx = Rm[0]*x + Rm[1]*y + Rm[2]*z + tv[0];
        float gy = Rm[3]*x + Rm[4]*y + Rm[5]*z + tv[1];
        float gz = Rm[6]*x + Rm[7]*y + Rm[8]*z + tv[2];
        kn += gx*gx + gy*gy + gz*gz;
      }
    }
    qnws[(size_t)bi * 12 + h] = qn;
    float pr = -hw * kn;
    unsigned short hi = f2b(pr);
    unsigned short lo = f2b(pr - b2f(hi));
    size_t base = (((size_t)bb2 * 12 + h) * 512 + jj) * 40;
    kb2[base + 28] = hi; kb2[base + 29] = lo;
    kb2[base + 30] = 0x3F80; kb2[base + 31] = 0x3F80;
  }
}

// ---------------- K3: qkpa per-(b,h) GEMM, 64-i chunks (192 blocks); f16 output ----------------
__global__ __launch_bounds__(256) void k_qkpa(
    const float* __restrict__ qws, const float* __restrict__ qgws,
    const float* __restrict__ qnws, const float* __restrict__ hwt,
    const float* __restrict__ mrow,
    const unsigned short* __restrict__ kb2,
    unsigned short* __restrict__ qkpa) {
  __shared__ unsigned short aq[64 * 40];
  __shared__ float mI[64];
  __shared__ float mJ[512];
  int bh = blockIdx.x;
  int b = bh / 12, h = bh - b * 12;
  int i0 = blockIdx.y * 64;
  int tid = threadIdx.x;
  float hw = 0.5f * logf(1.0f + __expf(hwt[h])) * 0.13608276348795434f;

  for (int idx = tid; idx < 512; idx += 256) mJ[idx] = mrow[b * 512 + idx];
  if (tid < 64) mI[tid] = mrow[b * 512 + i0 + tid];
  {
    int r = tid >> 2, c0 = (tid & 3) * 10;
    size_t gi = (size_t)b * 512 + i0 + r;
    const float* qr = qws + gi * 192 + h * 16;
    const float* gr = qgws + gi * 144 + h * 12;
    float pr = -hw * qnws[gi * 12 + h];
    unsigned short hi = f2b(pr);
    unsigned short lo = f2b(pr - b2f(hi));
    for (int c = c0; c < c0 + 10; c++) {
      unsigned short v;
      if (c < 16)      v = f2b(0.14433756729740643f * qr[c]);
      else if (c < 28) v = f2b(2.0f * hw * gr[c - 16]);
      else if (c < 30) v = 0x3F80;
      else if (c == 30) v = hi;
      else              v = lo;
      aq[r * 40 + c] = v;
    }
  }
  __syncthreads();

  int w = tid >> 6, l = tid & 63, lr = l & 15, lk = l >> 4;
  int n0 = w * 128;
  bf16x8 afr[4];
  #pragma unroll
  for (int mf = 0; mf < 4; mf++)
    afr[mf] = *(const bf16x8*)&aq[(mf * 16 + lr) * 40 + lk * 8];
  const unsigned short* kbb = kb2 + (size_t)bh * 512 * 40;
  #pragma unroll 2
  for (int nf = 0; nf < 8; nf++) {
    int j = n0 + nf * 16 + lr;
    float mjv = mJ[j];
    bf16x8 bfr = *(const bf16x8*)(kbb + (size_t)j * 40 + lk * 8);
    #pragma unroll
    for (int mf = 0; mf < 4; mf++) {
      f32x4 acc = {0.f, 0.f, 0.f, 0.f};
      acc = __builtin_amdgcn_mfma_f32_16x16x32_bf16(afr[mf], bfr, acc, 0, 0, 0);
      #pragma unroll
      for (int r = 0; r < 4; r++) {
        int il = mf * 16 + lk * 4 + r;
        int i = i0 + il;
        float val = acc[r] + 100000.0f * (mI[il] * mjv - 1.0f);
        val = fmaxf(val, -30000.0f);
        qkpa[((size_t)(b * 512 + i) * 12 + h) * 512 + j] = f2h(val);
      }
    }
  }
}

// ---------------- K4: fused per (b,i), chunked flash-style (exact R12/R16) ----------------
__global__ __launch_bounds__(512, 2) void k_attn(
    const float* __restrict__ z,
    const float* __restrict__ wb, const float* __restrict__ bb,
    const unsigned short* __restrict__ qkpa,
    unsigned short* __restrict__ attnG,
    unsigned short* __restrict__ feats) {
  __shared__ __align__(16) char zbfc[32768];
  __shared__ __align__(16) unsigned short attnbF[8192];
  __shared__ __align__(16) float logitsC[12][132];
  __shared__ unsigned short wbT[2048];
  __shared__ float bbl[16];
  __shared__ float mrun[12], lrun[12], frh[16], m_used[12][4], rinv[16];

  int tid = threadIdx.x;
  int bi = blockIdx.x;
  int b = bi >> 9;
  const float* zbase = z + (size_t)bi * 65536;
  int wv = tid >> 6, l = tid & 63, lr = l & 15, lk = l >> 4;

  if (tid < 16) bbl[tid] = (tid < 12) ? bb[tid] : 0.0f;
  else if (tid >= 16 && tid < 28) { mrun[tid - 16] = -1e30f; lrun[tid - 16] = 0.f; }
  else if (tid >= 28 && tid < 44) frh[tid - 28] = 1.0f;
  for (int idx = tid; idx < 2048; idx += 512) {
    int h = idx >> 7, c = idx & 127;
    wbT[h * 128 + c] = (h < 12) ? f2b(wb[c * 12 + h]) : (unsigned short)0;
  }
  __syncthreads();

  bf16x8 bfrag[4];
  #pragma unroll
  for (int kc = 0; kc < 4; kc++)
    bfrag[kc] = *(const bf16x8*)(wbT + lr * 128 + kc * 32 + lk * 8);

  f32x4 accPC = {0.f, 0.f, 0.f, 0.f};
  int c0 = wv * 16;

  #pragma unroll 1
  for (int ch = 0; ch < 4; ch++) {
    int j0 = ch * 128;
    {
      int jl = wv * 16 + lr;
      const float4* zp = (const float4*)(zbase + (size_t)(j0 + jl) * 128);
      float4 zr[8];
      #pragma unroll
      for (int q = 0; q < 8; q++) zr[q] = zp[(q >> 1) * 8 + lk * 2 + (q & 1)];
      f32x4 acc = {0.f, 0.f, 0.f, 0.f};
      #pragma unroll
      for (int kc = 0; kc < 4; kc++) {
        float4 a0 = zr[kc * 2], a1 = zr[kc * 2 + 1];
        unsigned int p0 = cvtpk(a0.x, a0.y), p1 = cvtpk(a0.z, a0.w);
        unsigned int p2 = cvtpk(a1.x, a1.y), p3 = cvtpk(a1.z, a1.w);
        u32x4 af = {p0, p1, p2, p3};
        acc = __builtin_amdgcn_mfma_f32_16x16x32_bf16(__builtin_bit_cast(bf16x8, af), bfrag[kc], acc, 0, 0, 0);
        int cb = kc * 32 + lk * 8;
        unsigned int pv[4] = {p0, p1, p2, p3};
        #pragma unroll
        for (int m = 0; m < 4; m++) {
          int cc = cb + 2 * m;
          *(unsigned short*)(zbfc + zaddrc(cc, jl))     = (unsigned short)(pv[m] & 0xffffu);
          *(unsigned short*)(zbfc + zaddrc(cc + 1, jl)) = (unsigned short)(pv[m] >> 16);
        }
      }
      if (lr < 12) {
        #pragma unroll
        for (int reg = 0; reg < 4; reg++)
          logitsC[lr][wv * 16 + lk * 4 + reg] = 0.5773502691896258f * (acc[reg] + bbl[lr]);
      }
    }
    __syncthreads();

    if (tid < 384) {
      int h = tid >> 5, g = tid & 31;
      float4 v = *(const float4*)&logitsC[h][g * 4];
      ushort4 qh = *(const ushort4*)(qkpa + (size_t)bi * 6144 + h * 512 + j0 + g * 4);
      v.x += h2f(qh.x); v.y += h2f(qh.y); v.z += h2f(qh.z); v.w += h2f(qh.w);
      float pmx = fmaxf(fmaxf(v.x, v.y), fmaxf(v.z, v.w));
      #pragma unroll
      for (int off = 16; off > 0; off >>= 1) pmx = fmaxf(pmx, __shfl_xor(pmx, off, 32));
      float m_old = mrun[h];
      float m_new = fmaxf(m_old, pmx);
      float fr = __expf(m_old - m_new);
      float4 e;
      e.x = __expf(v.x - m_new); e.y = __expf(v.y - m_new);
      e.z = __expf(v.z - m_new); e.w = __expf(v.w - m_new);
      float s = e.x + e.y + e.z + e.w;
      #pragma unroll
      for (int off = 16; off > 0; off >>= 1) s += __shfl_xor(s, off, 32);
      if (g == 0) {
        lrun[h] = lrun[h] * fr + s;
        mrun[h] = m_new;
        m_used[h][ch] = m_new;
        frh[h] = fr;
      }
      u32x2 ob;
      ob[0] = cvtpk(e.x, e.y); ob[1] = cvtpk(e.z, e.w);
      int j4 = j0 + g * 4;
      int byte = (h * 1024 + j4 * 2) ^ ((h & 7) << 4);
      *(u32x2*)((char*)attnbF + byte) = ob;
    }
    __syncthreads();

    {
      float fr = frh[lr];
      accPC[0] *= fr; accPC[1] *= fr; accPC[2] *= fr; accPC[3] *= fr;
      int arow = c0 + lr;
      #pragma unroll
      for (int jt = 0; jt < 4; jt++) {
        int jbl = jt * 32 + lk * 8;
        bf16x8 afrag = *(const bf16x8*)(zbfc + zaddrc(arow, jbl));
        int pb = (lr * 1024 + (j0 + jbl) * 2) ^ ((lr & 7) << 4);
        bf16x8 pfrag = *(const bf16x8*)((const char*)attnbF + pb);
        accPC = __builtin_amdgcn_mfma_f32_16x16x32_bf16(afrag, pfrag, accPC, 0, 0, 0);
      }
    }
    __syncthreads();
  }

  if (tid < 16) rinv[tid] = (tid < 12) ? (1.0f / lrun[tid]) : 0.0f;
  __syncthreads();

  size_t fb = (size_t)bi * 2112;

  if (tid < 384) {
    int h = tid >> 5, g = tid & 31;
    float rn = rinv[h];
    float mf = mrun[h];
    unsigned short* gout = attnG + (((size_t)(b * 12 + h) * 512) + (bi & 511)) * 512;
    #pragma unroll
    for (int ch = 0; ch < 4; ch++) {
      float sc = __expf(m_used[h][ch] - mf) * rn;
      int j4 = ch * 128 + g * 4;
      int byte = (h * 1024 + j4 * 2) ^ ((h & 7) << 4);
      u32x2 ob = *(const u32x2*)((const char*)attnbF + byte);
      float f0 = b2f((unsigned short)(ob[0] & 0xffffu)) * sc;
      float f1 = b2f((unsigned short)(ob[0] >> 16)) * sc;
      float f2 = b2f((unsigned short)(ob[1] & 0xffffu)) * sc;
      float f3 = b2f((unsigned short)(ob[1] >> 16)) * sc;
      u32x2 ow;
      ow[0] = cvtpk(f0, f1); ow[1] = cvtpk(f2, f3);
      *(u32x2*)(gout + j4) = ow;
    }
  }

  if (lr < 12) {
    float rn = rinv[lr];
    u32x2 ow;
    ow[0] = cvtpk(accPC[0] * rn, accPC[1] * rn);
    ow[1] = cvtpk(accPC[2] * rn, accPC[3] * rn);
    *(u32x2*)&feats[fb + 576 + lr * 128 + c0 + lk * 4] = ow;
  }
}

// ---------------- K5: [out_scalar | rpg] per-(b,h) GEMM, 64-i chunks (192 blocks) ----------------
__global__ __launch_bounds__(256) void k_av(
    const unsigned short* __restrict__ attnG, const unsigned short* __restrict__ vT,
    const float* __restrict__ rot, const float* __restrict__ trn,
    unsigned short* __restrict__ feats) {
  __shared__ float sc[64 * 24];
  __shared__ float rotL[64 * 9];
  __shared__ float trnL[64 * 3];
  int bh = blockIdx.x;
  int b = bh / 12, h = bh - b * 12;
  int i0 = blockIdx.y * 64;
  int tid = threadIdx.x;

  for (int idx = tid; idx < 576; idx += 256) rotL[idx] = rot[((size_t)b * 512 + i0) * 9 + idx];
  for (int idx = tid; idx < 192; idx += 256) trnL[idx] = trn[((size_t)b * 512 + i0) * 3 + idx];

  int w = tid >> 6, l = tid & 63, lr = l & 15, lk = l >> 4;
  int iw = w * 16;
  const unsigned short* Abase = attnG + ((size_t)bh * 512 + i0 + iw) * 512;
  const unsigned short* vTb = vT + (size_t)b * 480 * 512;
  int cm[3];
  #pragma unroll
  for (int nf = 0; nf < 3; nf++) {
    int c = nf * 16 + lr;
    cm[nf] = (c < 16) ? (h * 16 + c) : (c < 40 ? 192 + h * 24 + (c - 16) : 0);
  }
  f32x4 acc[3] = {};
  #pragma unroll 2
  for (int jb = 0; jb < 512; jb += 32) {
    bf16x8 a0 = *(const bf16x8*)(Abase + (size_t)lr * 512 + jb + lk * 8);
    #pragma unroll
    for (int nf = 0; nf < 3; nf++) {
      bf16x8 bfr = *(const bf16x8*)(vTb + (size_t)cm[nf] * 512 + jb + lk * 8);
      acc[nf] = __builtin_amdgcn_mfma_f32_16x16x32_bf16(a0, bfr, acc[nf], 0, 0, 0);
    }
  }
  #pragma unroll
  for (int nf = 0; nf < 3; nf++) {
    int c = nf * 16 + lr;
    #pragma unroll
    for (int r = 0; r < 4; r++) {
      int il = iw + lk * 4 + r;
      float v = acc[nf][r];
      if (c < 16) feats[(size_t)(b * 512 + i0 + il) * 2112 + h * 16 + c] = f2b(v);
      else if (c < 40) sc[il * 24 + (c - 16)] = v;
    }
  }
  __syncthreads();
  #pragma unroll
  for (int k2 = 0; k2 < 2; k2++) {
    int itm = tid + k2 * 256;
    int il = itm >> 3, pv = itm & 7;
    float gx = sc[il * 24 + pv * 3 + 0] - trnL[il * 3 + 0];
    float gy = sc[il * 24 + pv * 3 + 1] - trnL[il * 3 + 1];
    float gz = sc[il * 24 + pv * 3 + 2] - trnL[il * 3 + 2];
    const float* R = &rotL[il * 9];
    float lx = R[0] * gx + R[3] * gy + R[6] * gz;
    float ly = R[1] * gx + R[4] * gy + R[7] * gz;
    float lz = R[2] * gx + R[5] * gy + R[8] * gz;
    size_t fb = (size_t)(b * 512 + i0 + il) * 2112;
    feats[fb + 192 + h * 8 + pv] = f2b(lx);
    feats[fb + 288 + h * 8 + pv] = f2b(ly);
    feats[fb + 384 + h * 8 + pv] = f2b(lz);
    feats[fb + 480 + h * 8 + pv] = f2b(sqrtf(lx * lx + ly * ly + lz * lz + 1e-8f));
  }
}

// ---------------- K6: out = (feats @ wout + bout) * mask, 64x32 tiles ----------------
__global__ __launch_bounds__(256) void k_out(const unsigned short* __restrict__ feats,
                                             const unsigned short* __restrict__ woutT,
                                             const float* __restrict__ bout,
                                             const float* __restrict__ mrow,
                                             float* __restrict__ out) {
  __shared__ unsigned short At[2048];
  __shared__ unsigned short Bt[1024];
  int m0 = blockIdx.x * 64, n0 = blockIdx.y * 32;
  int tid = threadIdx.x;
  int wv = tid >> 6, l = tid & 63, lr = l & 15, lk = l >> 4;
  int wm = wv >> 1, wn = wv & 1;
  f32x4 acc[2] = {};
  int sr = tid >> 2, sq = tid & 3;
  const char* fbase = (const char*)feats + (size_t)(m0 + sr) * 4224 + sq * 16;
  int swA = (sr * 64 + sq * 16) ^ ((sr & 7) << 4);
  int rb = tid >> 2, qb = tid & 3;
  const char* bbase = (const char*)woutT + (size_t)(n0 + rb) * 4224 + qb * 16;
  int swB = (rb * 64 + qb * 16) ^ ((rb & 7) << 4);

  uint4 av = *(const uint4*)(fbase);
  uint4 bv = {0, 0, 0, 0};
  if (tid < 128) bv = *(const uint4*)(bbase);
  for (int k0 = 0; k0 < 2112; k0 += 32) {
    __syncthreads();
    *(uint4*)((char*)At + swA) = av;
    if (tid < 128) *(uint4*)((char*)Bt + swB) = bv;
    __syncthreads();
    if (k0 + 32 < 2112) {
      av = *(const uint4*)(fbase + (size_t)(k0 + 32) * 2);
      if (tid < 128) bv = *(const uint4*)(bbase + (size_t)(k0 + 32) * 2);
    }
    bf16x8 af[2], bfv;
    #pragma unroll
    for (int mt = 0; mt < 2; mt++) {
      int row = wm * 32 + mt * 16 + lr;
      af[mt] = *(const bf16x8*)((const char*)At + ((row * 64 + lk * 16) ^ ((row & 7) << 4)));
    }
    {
      int row = wn * 16 + lr;
      bfv = *(const bf16x8*)((const char*)Bt + ((row * 64 + lk * 16) ^ ((row & 7) << 4)));
    }
    #pragma unroll
    for (int mt = 0; mt < 2; mt++)
      acc[mt] = __builtin_amdgcn_mfma_f32_16x16x32_bf16(af[mt], bfv, acc[mt], 0, 0, 0);
  }

  #pragma unroll
  for (int mt = 0; mt < 2; mt++) {
    int nc = n0 + wn * 16 + lr;
    float bo = bout[nc];
    #pragma unroll
    for (int reg = 0; reg < 4; reg++) {
      int rowg = m0 + wm * 32 + mt * 16 + lk * 4 + reg;
      out[(size_t)rowg * 384 + nc] = (acc[mt][reg] + bo) * mrow[rowg];
    }
  }
}

extern "C" void kernel_launch(void* const* d_in, const int* in_sizes, int n_in,
                              void* d_out, int out_size, void* d_ws, size_t ws_size,
                              hipStream_t stream) {
  const float* s    = (const float*)d_in[0];
  const float* z    = (const float*)d_in[1];
  const float* rot  = (const float*)d_in[2];
  const float* trn  = (const float*)d_in[3];
  const float* msk  = (const float*)d_in[4];
  const float* wq   = (const float*)d_in[5];
  const float* bq   = (const float*)d_in[6];
  const float* wkv  = (const float*)d_in[7];
  const float* bkv  = (const float*)d_in[8];
  const float* wqp  = (const float*)d_in[9];
  const float* bqp  = (const float*)d_in[10];
  const float* wkvp = (const float*)d_in[11];
  const float* bkvp = (const float*)d_in[12];
  const float* wb   = (const float*)d_in[13];
  const float* bb   = (const float*)d_in[14];
  const float* wout = (const float*)d_in[15];
  const float* bout = (const float*)d_in[16];
  const float* hwt  = (const float*)d_in[17];

  float* qws  = (float*)d_ws;                               // 196608 f32
  float* qgws = qws + 196608;                               // 147456 f32
  float* qnws = qgws + 147456;                              // 12288 f32
  float* rawp = qnws + 12288;                               // 589824 f32
  unsigned short* qkpa  = (unsigned short*)(rawp + 589824); // 6291456 u16 (f16)
  unsigned short* vT    = qkpa + 6291456;                   // 491520 u16
  unsigned short* kb2   = vT + 491520;                      // 491520 u16
  unsigned short* attnG = kb2 + 491520;                     // 6291456 u16
  unsigned short* feats = attnG + 6291456;                  // 2162688 u16
  unsigned short* woutT = feats + 2162688;                  // 811008 u16
  unsigned short* WT    = woutT + 811008;                   // 442368 u16
  float* out = (float*)d_out;

  k_prep<<<dim3(1224), dim3(256), 0, stream>>>(wout, woutT, wq, wkv, wqp, wkvp, WT);
  k_projG<<<dim3(16, 18), dim3(256), 0, stream>>>(s, WT, bq, bkv, bqp, bkvp,
                                                  qws, kb2, vT, rawp);
  k_points<<<dim3(256), dim3(512), 0, stream>>>(rawp, rot, trn, hwt, qgws, qnws, kb2, vT);
  k_qkpa<<<dim3(24, 8), dim3(256), 0, stream>>>(qws, qgws, qnws, hwt, msk, kb2, qkpa);
  k_attn<<<dim3(1024), dim3(512), 0, stream>>>(z, wb, bb, qkpa, attnG, feats);
  k_av<<<dim3(24, 8), dim3(256), 0, stream>>>(attnG, vT, rot, trn, feats);
  k_out<<<dim3(16, 12), dim3(256), 0, stream>>>(feats, woutT, bout, msk, out);
}